// Round 8
// baseline (2947.923 us; speedup 1.0000x reference)
//
#include <hip/hip_runtime.h>
#include <math.h>

#define N_TOTAL    262144
#define NUM_SAMPLE 1024
#define FPS_BLOCKS 64
#define FPS_THREADS 256
#define FPS_PPT (N_TOTAL / (FPS_BLOCKS * FPS_THREADS))   // 16
#define M_WAVE 8                                          // published cands per wave
#define POOL (FPS_BLOCKS * 4 * M_WAVE)                    // 2048
#define ENT_PER_T (POOL / FPS_THREADS)                    // 8
#define CPL (POOL / 64)                                   // 32 cands per lane (wave0)
#define SEL_CAP 1023

__device__ __forceinline__ float addrn(float a, float b) { return __fadd_rn(a, b); }
__device__ __forceinline__ float subrn(float a, float b) { return __fsub_rn(a, b); }
__device__ __forceinline__ float mulrn(float a, float b) { return __fmul_rn(a, b); }

__device__ __forceinline__ float d2rn(float ax, float ay, float az,
                                      float bx, float by, float bz) {
  float dx = subrn(ax, bx), dy = subrn(ay, by), dz = subrn(az, bz);
  return addrn(addrn(mulrn(dx, dx), mulrn(dy, dy)), mulrn(dz, dz));
}

// ---- DPP wave64 reduce-to-lane63 + readlane broadcast (pure VALU) ----
template <int CTRL>
__device__ __forceinline__ int dpp_i(int x) {
  return __builtin_amdgcn_update_dpp(x, x, CTRL, 0xF, 0xF, false);
}
template <int CTRL>
__device__ __forceinline__ unsigned long long dpp_u64(unsigned long long v) {
  unsigned lo = (unsigned)v, hi = (unsigned)(v >> 32);
  unsigned olo = (unsigned)dpp_i<CTRL>((int)lo);
  unsigned ohi = (unsigned)dpp_i<CTRL>((int)hi);
  return ((unsigned long long)ohi << 32) | olo;
}
__device__ __forceinline__ unsigned long long wave_u64max_bcast(unsigned long long v) {
  unsigned long long o;
  o = dpp_u64<0x111>(v); if (o > v) v = o;   // row_shr:1
  o = dpp_u64<0x112>(v); if (o > v) v = o;   // row_shr:2
  o = dpp_u64<0x114>(v); if (o > v) v = o;   // row_shr:4
  o = dpp_u64<0x118>(v); if (o > v) v = o;   // row_shr:8
  o = dpp_u64<0x142>(v); if (o > v) v = o;   // row_bcast:15
  o = dpp_u64<0x143>(v); if (o > v) v = o;   // row_bcast:31
  unsigned lo = (unsigned)__builtin_amdgcn_readlane((int)(unsigned)v, 63);
  unsigned hi = (unsigned)__builtin_amdgcn_readlane((int)(unsigned)(v >> 32), 63);
  return ((unsigned long long)hi << 32) | lo;
}
__device__ __forceinline__ unsigned wave_umax_bcast(unsigned v) {
  unsigned o;
  o = (unsigned)dpp_i<0x111>((int)v); v = (o > v) ? o : v;
  o = (unsigned)dpp_i<0x112>((int)v); v = (o > v) ? o : v;
  o = (unsigned)dpp_i<0x114>((int)v); v = (o > v) ? o : v;
  o = (unsigned)dpp_i<0x118>((int)v); v = (o > v) ? o : v;
  o = (unsigned)dpp_i<0x142>((int)v); v = (o > v) ? o : v;
  o = (unsigned)dpp_i<0x143>((int)v); v = (o > v) ? o : v;
  return (unsigned)__builtin_amdgcn_readlane((int)v, 63);
}

// ---------------- LAPACK emulation (f32) ----------------
__device__ __forceinline__ float slapy2f(float x, float y) {
  float xa = fabsf(x), ya = fabsf(y);
  float w = fmaxf(xa, ya), z = fminf(xa, ya);
  if (z == 0.f) return w;
  float t = z / w;
  return w * __fsqrt_rn(1.f + t * t);
}

__device__ __forceinline__ void slartgf(float f, float g, float& c, float& s, float& r) {
  if (g == 0.f) { c = 1.f; s = 0.f; r = f; }
  else if (f == 0.f) { c = 0.f; s = (g > 0.f) ? 1.f : -1.f; r = fabsf(g); }
  else {
    float d = __fsqrt_rn(f * f + g * g);
    c = fabsf(f) / d;
    r = (f >= 0.f) ? d : -d;
    s = g / r;
  }
}

__device__ void slaev2f(float a, float b, float c0, float& rt1, float& rt2,
                        float& cs1, float& sn1) {
  float sm = a + c0, df = a - c0;
  float adf = fabsf(df), tb = b + b, ab = fabsf(tb);
  float acmx, acmn;
  if (fabsf(a) > fabsf(c0)) { acmx = a; acmn = c0; } else { acmx = c0; acmn = a; }
  float rt;
  if (adf > ab)      { float t = ab / adf; rt = adf * __fsqrt_rn(1.f + t * t); }
  else if (adf < ab) { float t = adf / ab; rt = ab * __fsqrt_rn(1.f + t * t); }
  else               { rt = ab * __fsqrt_rn(2.f); }
  int sgn1;
  if (sm < 0.f)      { rt1 = 0.5f * (sm - rt); sgn1 = -1; rt2 = (acmx / rt1) * acmn - (b / rt1) * b; }
  else if (sm > 0.f) { rt1 = 0.5f * (sm + rt); sgn1 = 1;  rt2 = (acmx / rt1) * acmn - (b / rt1) * b; }
  else               { rt1 = 0.5f * rt; rt2 = -0.5f * rt; sgn1 = 1; }
  float cs; int sgn2;
  if (df >= 0.f) { cs = df + rt; sgn2 = 1; } else { cs = df - rt; sgn2 = -1; }
  float acs = fabsf(cs);
  if (acs > ab) {
    float ct = -tb / cs;
    sn1 = 1.f / __fsqrt_rn(1.f + ct * ct);
    cs1 = ct * sn1;
  } else {
    if (ab == 0.f) { cs1 = 1.f; sn1 = 0.f; }
    else { float tn = -cs / tb; cs1 = 1.f / __fsqrt_rn(1.f + tn * tn); sn1 = tn * cs1; }
  }
  if (sgn1 == sgn2) { float tn = cs1; cs1 = -sn1; sn1 = tn; }
}

#define D_(i) d[(i)-1]
#define E_(i) e[(i)-1]

__device__ void ssteqr3(float d[3], float e[2], float Z[3][3]) {
  const float eps    = 5.9604645e-08f;
  const float eps2   = 3.5527137e-15f;
  const float safmin = 1.17549435e-38f;
  const float ssfmax = 3.0744573e+18f;
  const float ssfmin = 3.0517578e-05f;
  const int n = 3;
  int jtot = 0, nmaxit = 90;
  int l1 = 1;

  while (true) {
    if (l1 > n) break;
    if (l1 > 1) E_(l1 - 1) = 0.f;
    int m = n;
    for (int mm = l1; mm <= n - 1; ++mm) {
      float tst = fabsf(E_(mm));
      if (tst == 0.f) { m = mm; break; }
      if (tst <= (__fsqrt_rn(fabsf(D_(mm))) * __fsqrt_rn(fabsf(D_(mm + 1)))) * eps) {
        E_(mm) = 0.f; m = mm; break;
      }
    }
    int l = l1, lsv = l, lend = m, lendsv = m;
    l1 = m + 1;
    if (lend == l) continue;

    float anorm = fabsf(D_(lend));
    for (int i2 = l; i2 <= lend - 1; ++i2) {
      anorm = fmaxf(anorm, fabsf(D_(i2)));
      anorm = fmaxf(anorm, fabsf(E_(i2)));
    }
    int iscale = 0;
    if (anorm == 0.f) continue;
    if (anorm > ssfmax) {
      iscale = 1; float mul = ssfmax / anorm;
      for (int i2 = l; i2 <= lend; ++i2) D_(i2) *= mul;
      for (int i2 = l; i2 <= lend - 1; ++i2) E_(i2) *= mul;
    } else if (anorm < ssfmin) {
      iscale = 2; float mul = ssfmin / anorm;
      for (int i2 = l; i2 <= lend; ++i2) D_(i2) *= mul;
      for (int i2 = l; i2 <= lend - 1; ++i2) E_(i2) *= mul;
    }

    if (fabsf(D_(lend)) < fabsf(D_(l))) { int t = l; l = lend; lend = t; }

    if (lend > l) {
      while (true) {
        int m2 = lend;
        if (l != lend) {
          for (int mm = l; mm <= lend - 1; ++mm) {
            float tst = fabsf(E_(mm)); tst = tst * tst;
            if (tst <= (eps2 * fabsf(D_(mm))) * fabsf(D_(mm + 1)) + safmin) { m2 = mm; break; }
          }
        }
        if (m2 < lend) E_(m2) = 0.f;
        float p = D_(l);
        if (m2 == l) { D_(l) = p; l = l + 1; if (l <= lend) continue; break; }
        if (m2 == l + 1) {
          float rt1, rt2, cc, ss;
          slaev2f(D_(l), E_(l), D_(l + 1), rt1, rt2, cc, ss);
          for (int i2 = 0; i2 < 3; ++i2) {
            float tmp = Z[i2][l];
            Z[i2][l]     = cc * tmp - ss * Z[i2][l - 1];
            Z[i2][l - 1] = ss * tmp + cc * Z[i2][l - 1];
          }
          D_(l) = rt1; D_(l + 1) = rt2; E_(l) = 0.f;
          l = l + 2; if (l <= lend) continue; break;
        }
        if (jtot == nmaxit) break;
        ++jtot;
        float g = (D_(l + 1) - p) / (2.f * E_(l));
        float r = slapy2f(g, 1.f);
        float sgn_rg = (g >= 0.f) ? r : -r;
        g = D_(m2) - p + E_(l) / (g + sgn_rg);
        float s = 1.f, c = 1.f;
        p = 0.f;
        float csv[2], ssv[2];
        for (int i2 = m2 - 1; i2 >= l; --i2) {
          float f = s * E_(i2);
          float b = c * E_(i2);
          slartgf(g, f, c, s, r);
          if (i2 != m2 - 1) E_(i2 + 1) = r;
          g = D_(i2 + 1) - p;
          r = (D_(i2) - g) * s + 2.f * c * b;
          p = s * r;
          D_(i2 + 1) = g + p;
          g = c * r - b;
          csv[i2 - l] = c; ssv[i2 - l] = -s;
        }
        for (int j = m2 - 1; j >= l; --j) {
          float ct = csv[j - l], st = ssv[j - l];
          for (int i2 = 0; i2 < 3; ++i2) {
            float tmp = Z[i2][j];
            Z[i2][j]     = ct * tmp - st * Z[i2][j - 1];
            Z[i2][j - 1] = st * tmp + ct * Z[i2][j - 1];
          }
        }
        D_(l) = D_(l) - p;
        E_(l) = g;
      }
    } else {
      while (true) {
        int m2 = lend;
        if (l != lend) {
          for (int mm = l; mm >= lend + 1; --mm) {
            float tst = fabsf(E_(mm - 1)); tst = tst * tst;
            if (tst <= (eps2 * fabsf(D_(mm))) * fabsf(D_(mm - 1)) + safmin) { m2 = mm; break; }
          }
        }
        if (m2 > lend) E_(m2 - 1) = 0.f;
        float p = D_(l);
        if (m2 == l) { D_(l) = p; l = l - 1; if (l >= lend) continue; break; }
        if (m2 == l - 1) {
          float rt1, rt2, cc, ss;
          slaev2f(D_(l - 1), E_(l - 1), D_(l), rt1, rt2, cc, ss);
          for (int i2 = 0; i2 < 3; ++i2) {
            float tmp = Z[i2][l - 1];
            Z[i2][l - 1] = cc * tmp - ss * Z[i2][l - 2];
            Z[i2][l - 2] = ss * tmp + cc * Z[i2][l - 2];
          }
          D_(l - 1) = rt1; D_(l) = rt2; E_(l - 1) = 0.f;
          l = l - 2; if (l >= lend) continue; break;
        }
        if (jtot == nmaxit) break;
        ++jtot;
        float g = (D_(l - 1) - p) / (2.f * E_(l - 1));
        float r = slapy2f(g, 1.f);
        float sgn_rg = (g >= 0.f) ? r : -r;
        g = D_(m2) - p + E_(l - 1) / (g + sgn_rg);
        float s = 1.f, c = 1.f;
        p = 0.f;
        float csv[2], ssv[2];
        for (int i2 = m2; i2 <= l - 1; ++i2) {
          float f = s * E_(i2);
          float b = c * E_(i2);
          slartgf(g, f, c, s, r);
          if (i2 != m2) E_(i2 - 1) = r;
          g = D_(i2) - p;
          r = (D_(i2 + 1) - g) * s + 2.f * c * b;
          p = s * r;
          D_(i2) = g + p;
          g = c * r - b;
          csv[i2 - m2] = c; ssv[i2 - m2] = s;
        }
        for (int j = m2; j <= l - 1; ++j) {
          float ct = csv[j - m2], st = ssv[j - m2];
          for (int i2 = 0; i2 < 3; ++i2) {
            float tmp = Z[i2][j];
            Z[i2][j]     = ct * tmp - st * Z[i2][j - 1];
            Z[i2][j - 1] = st * tmp + ct * Z[i2][j - 1];
          }
        }
        D_(l) = D_(l) - p;
        E_(l - 1) = g;
      }
    }
    if (iscale == 1) {
      float mul = anorm / ssfmax;
      for (int i2 = lsv; i2 <= lendsv; ++i2) D_(i2) *= mul;
      for (int i2 = lsv; i2 <= lendsv - 1; ++i2) E_(i2) *= mul;
    } else if (iscale == 2) {
      float mul = anorm / ssfmin;
      for (int i2 = lsv; i2 <= lendsv; ++i2) D_(i2) *= mul;
      for (int i2 = lsv; i2 <= lendsv - 1; ++i2) E_(i2) *= mul;
    }
  }
  for (int ii = 2; ii <= n; ++ii) {
    int i2 = ii - 1, k = i2;
    float p = D_(i2);
    for (int j = ii; j <= n; ++j) if (D_(j) < p) { k = j; p = D_(j); }
    if (k != i2) {
      D_(k) = D_(i2); D_(i2) = p;
      for (int rr = 0; rr < 3; ++rr) {
        float t = Z[rr][i2 - 1]; Z[rr][i2 - 1] = Z[rr][k - 1]; Z[rr][k - 1] = t;
      }
    }
  }
}

__device__ void eigh3_smallest(float a00, float a10, float a20, float a11, float a21, float a22,
                               float& nx, float& ny, float& nz) {
  float d[3], e[2];
  float Z[3][3] = {{1.f,0.f,0.f},{0.f,1.f,0.f},{0.f,0.f,1.f}};
  float tau, v2;
  {
    float alpha = a10, x = a20;
    float xnorm = fabsf(x);
    if (xnorm == 0.f) {
      tau = 0.f; v2 = 0.f;
      d[0] = a00; d[1] = a11; d[2] = a22;
      e[0] = alpha; e[1] = a21;
    } else {
      float beta = -copysignf(slapy2f(alpha, x), alpha);
      tau = (beta - alpha) / beta;
      v2 = x / (alpha - beta);
      float w0 = (tau * a11) + tau * (a21 * v2);
      float w1 = (tau * a21) + (tau * v2) * a22;
      float ac = (-0.5f * tau) * (w0 + w1 * v2);
      w0 = w0 + ac;
      w1 = w1 + ac * v2;
      d[0] = a00;
      d[1] = (a11 - w0) - w0;
      d[2] = (a22 - v2 * w1) - w1 * v2;
      e[0] = beta;
      e[1] = (a21 - v2 * w0) - w1;
    }
  }
  ssteqr3(d, e, Z);
  if (tau != 0.f) {
    for (int c = 0; c < 3; ++c) {
      float w = Z[1][c] + Z[2][c] * v2;
      float temp = (-tau) * w;
      Z[1][c] = Z[1][c] + temp;
      Z[2][c] = Z[2][c] + v2 * temp;
    }
  }
  nx = Z[0][0]; ny = Z[1][0]; nz = Z[2][0];
}

// ---------------- K0: init workspace ----------------
__global__ void k0_init(unsigned long long* cand, int* sample_idx) {
  int t = blockIdx.x * blockDim.x + threadIdx.x;
  if (t < 2 * POOL) cand[t] = 0ull;
  if (t == 0) sample_idx[0] = 0;
}

// ---------------- K1: batched FPS, barrier-free wave0 pick loop ----------------
// Per batch: every wave builds+publishes its top-8 (u64 DPP argmax, lex order
// (md desc, point-index asc) via key (mdbits<<32)|idf, idf = 0x3FFFFF - index,
// md>=0 so bit order == float order). All 256 threads poll their 8 pool words
// into LDS (keys + xyz fetched bit-exact from pos). Then WAVE 0 ONLY holds the
// full 2048-entry pool in registers (32/lane) and runs the pick loop with zero
// barriers: lane scan -> u64 DPP max-bcast -> continue iff keyWin >= Tkey
// (T = max over 256 waves of their 8th-best; unpublished points <= their
// wave's 8th and md only decreases -> picks bit-exact) -> owner-entry DPP ->
// uniform LDS xyz read -> in-register min updates. sample_idx/sel stores stay
// outstanding; single batch-end barrier drains them.
__global__ __launch_bounds__(FPS_THREADS) void k1_fps(
    const float* __restrict__ pos,
    unsigned long long* __restrict__ cand,
    int* __restrict__ sample_idx) {
  __shared__ unsigned long long keyl[POOL];
  __shared__ float pxl[POOL], pyl[POOL], pzl[POOL];
  __shared__ float sel_x[SEL_CAP], sel_y[SEL_CAP], sel_z[SEL_CAP];
  __shared__ int sh_selcnt;

  const int tidx = threadIdx.x;
  const int lane = tidx & 63, wv = tidx >> 6;
  const int gtid = blockIdx.x * FPS_THREADS + tidx;

  float px[FPS_PPT], py[FPS_PPT], pz[FPS_PPT], md[FPS_PPT];
#pragma unroll
  for (int k = 0; k < FPS_PPT; ++k) {
    int p = gtid + k * (FPS_BLOCKS * FPS_THREADS);
    px[k] = pos[3 * p]; py[k] = pos[3 * p + 1]; pz[k] = pos[3 * p + 2];
    md[k] = 1e10f;
  }
  const unsigned idf0 = 0x3FFFFFu - (unsigned)gtid;
  if (tidx == 0) { sel_x[0] = pos[0]; sel_y[0] = pos[1]; sel_z[0] = pos[2]; }
  __syncthreads();
  int sel_cnt = 1, total = 0, bt = 0;
  while (total < NUM_SAMPLE - 1) {
    ++bt;
    // ---- Phase A: owner md updates vs previous batch's picks ----
    for (int s = 0; s < sel_cnt; ++s) {
      float lx = sel_x[s], ly = sel_y[s], lz = sel_z[s];
#pragma unroll
      for (int k = 0; k < FPS_PPT; ++k)
        md[k] = fminf(md[k], d2rn(px[k], py[k], pz[k], lx, ly, lz));
    }
    // ---- per-wave top-8 build + publish (u64 DPP argmax, barrier-free) ----
    const unsigned tag = (unsigned)bt & 1023u;
    unsigned long long* setbase = cand + (size_t)(bt & 1) * POOL;
    {
      float wmd[FPS_PPT];
#pragma unroll
      for (int k = 0; k < FPS_PPT; ++k) wmd[k] = md[k];
      unsigned long long mypub = 0ull;
      for (int r = 0; r < M_WAVE; ++r) {
        float bm = wmd[0]; unsigned bf = idf0;
#pragma unroll
        for (int k = 1; k < FPS_PPT; ++k) {
          unsigned idfk = idf0 - ((unsigned)k << 14);
          bool t = (wmd[k] > bm) || (wmd[k] == bm && idfk > bf);
          if (t) { bm = wmd[k]; bf = idfk; }
        }
        unsigned long long kk = (bm < 0.f) ? 0ull
            : (((unsigned long long)__float_as_uint(bm) << 32) | bf);
        unsigned long long kw = wave_u64max_bcast(kk);
        if (lane == r)
          mypub = (kw & 0xFFFFFFFF00000000ull) | ((kw & 0x3FFFFFull) << 10);
        unsigned wmbits = (unsigned)(kw >> 32);
        unsigned widf = (unsigned)(kw & 0x3FFFFFull);
#pragma unroll
        for (int k = 0; k < FPS_PPT; ++k) {
          unsigned idfk = idf0 - ((unsigned)k << 14);
          if (__float_as_uint(wmd[k]) == wmbits && idfk == widf) wmd[k] = -1.f;
        }
      }
      if (lane < M_WAVE)
        __hip_atomic_store(setbase + blockIdx.x * (4 * M_WAVE) + wv * M_WAVE + lane,
                           mypub | tag, __ATOMIC_RELAXED, __HIP_MEMORY_SCOPE_AGENT);
    }
    // ---- Phase B: poll own 8 words; stage keys + bit-exact xyz into LDS ----
    {
      const int base_w = tidx * ENT_PER_T;
      unsigned done = 0;
      while (done != 0xFFu) {
#pragma unroll
        for (int j = 0; j < ENT_PER_T; ++j) {
          if (!((done >> j) & 1u)) {
            unsigned long long v = __hip_atomic_load(setbase + base_w + j,
                                                     __ATOMIC_RELAXED, __HIP_MEMORY_SCOPE_AGENT);
            if ((unsigned)(v & 1023ull) == tag) {
              done |= 1u << j;
              unsigned long long vv = v & ~1023ull;
              keyl[base_w + j] = vv;
              int gidx = 0x3FFFFF - (int)((vv >> 10) & 0x3FFFFFull);
              pxl[base_w + j] = pos[3 * gidx];
              pyl[base_w + j] = pos[3 * gidx + 1];
              pzl[base_w + j] = pos[3 * gidx + 2];
            }
          }
        }
        if (done != 0xFFu) __builtin_amdgcn_s_sleep(1);
      }
    }
    __syncthreads();   // pool staged
    // ---- Phase C: wave0-only, barrier-free pick loop ----
    if (wv == 0) {
      float cmd[CPL]; unsigned cidf[CPL];
      float cx[CPL], cy[CPL], cz[CPL];
#pragma unroll
      for (int j = 0; j < CPL; ++j) {
        int e = j * 64 + lane;
        unsigned long long v = keyl[e];
        cmd[j] = __uint_as_float((unsigned)(v >> 32));
        cidf[j] = (unsigned)((v >> 10) & 0x3FFFFFull);
        cx[j] = pxl[e]; cy[j] = pyl[e]; cz[j] = pzl[e];
      }
      // T = max over 256 waves of their rank-7 entry (e%8==7 <=> lane%8==7)
      unsigned long long Tkey;
      {
        unsigned long long tk = 0ull;
        if ((lane & 7) == 7) {
          float bm = cmd[0]; unsigned bf = cidf[0];
#pragma unroll
          for (int j = 1; j < CPL; ++j) {
            bool t = (cmd[j] > bm) || (cmd[j] == bm && cidf[j] > bf);
            if (t) { bm = cmd[j]; bf = cidf[j]; }
          }
          tk = ((unsigned long long)__float_as_uint(bm) << 32) | bf;
        }
        Tkey = wave_u64max_bcast(tk);
      }
      int picks = 0;
      const int room = (NUM_SAMPLE - 1) - total;
      for (;;) {
        float bm = cmd[0]; unsigned bf = cidf[0]; int bj = 0;
#pragma unroll
        for (int j = 1; j < CPL; ++j) {
          bool t = (cmd[j] > bm) || (cmd[j] == bm && cidf[j] > bf);
          if (t) { bm = cmd[j]; bf = cidf[j]; bj = j; }
        }
        unsigned long long mykey = (bm < 0.f) ? 0ull
            : (((unsigned long long)__float_as_uint(bm) << 32) | bf);
        unsigned long long keyWin = wave_u64max_bcast(mykey);
        if (keyWin < Tkey || picks >= room) break;
        // owner entry index (unique: idf unique per point/batch)
        unsigned ew = wave_umax_bcast((mykey == keyWin)
                                      ? (unsigned)(bj * 64 + lane + 1) : 0u) - 1u;
        float Xp = pxl[ew], Yp = pyl[ew], Zp = pzl[ew];   // uniform LDS broadcast
        unsigned gidf = (unsigned)(keyWin & 0x3FFFFFull);
        if (lane == 0) {
          sel_x[picks] = Xp; sel_y[picks] = Yp; sel_z[picks] = Zp;
          if (blockIdx.x == 0) sample_idx[1 + total + picks] = 0x3FFFFF - (int)gidf;
        }
#pragma unroll
        for (int j = 0; j < CPL; ++j) {
          float d2 = d2rn(cx[j], cy[j], cz[j], Xp, Yp, Zp);
          float nm = fminf(cmd[j], d2);
          cmd[j] = (cidf[j] == gidf) ? -1.f : nm;   // remove winner; exact min
        }
        ++picks;
      }
      if (lane == 0) sh_selcnt = picks;
    }
    __syncthreads();   // batch end: sel list + selcnt + stores drained
    sel_cnt = sh_selcnt;
    total += sel_cnt;
  }
}

// ---------------- K2a: wave-per-sample KNN + covariance + eigh -> feats9 ----------------
__global__ __launch_bounds__(256) void k2a_knn(
    const float* __restrict__ pos, const float* __restrict__ col,
    const int* __restrict__ sample_idx,
    float4* __restrict__ sp4g, float* __restrict__ feats9) {
  __shared__ float4 sp[NUM_SAMPLE];
  const int tid = threadIdx.x, lane = tid & 63, wv = tid >> 6;
  for (int i = tid; i < NUM_SAMPLE; i += 256) {
    int idx = sample_idx[i];
    float x = pos[3 * idx], y = pos[3 * idx + 1], z = pos[3 * idx + 2];
    float nrm = addrn(addrn(mulrn(x, x), mulrn(y, y)), mulrn(z, z));
    float4 v = make_float4(x, y, z, nrm);
    sp[i] = v;
    if (blockIdx.x == 0) sp4g[i] = v;
  }
  __syncthreads();
  for (int it = 0; it < 4; ++it) {
    const int r = blockIdx.x * 16 + wv * 4 + it;
    float4 pr = sp[r];
    unsigned long long kk[16];
#pragma unroll
    for (int k = 0; k < 16; ++k) {
      int j = lane + 64 * k;
      float4 q = sp[j];
      float dot = fmaf(pr.z, q.z, fmaf(pr.y, q.y, mulrn(pr.x, q.x)));
      float d2 = subrn(addrn(pr.w, q.w), mulrn(2.f, dot));
      unsigned b = __float_as_uint(d2);
      unsigned sbits = (b & 0x80000000u) ? ~b : (b | 0x80000000u);
      kk[k] = ((unsigned long long)sbits << 32) | (unsigned)j;
    }
    int bi[17];
#pragma unroll
    for (int rsel = 0; rsel < 17; ++rsel) {
      unsigned long long best = 0xFFFFFFFFFFFFFFFFull;
#pragma unroll
      for (int k = 0; k < 16; ++k) best = (kk[k] < best) ? kk[k] : best;
#pragma unroll
      for (int mk = 1; mk < 64; mk <<= 1) {
        unsigned long long o = (unsigned long long)__shfl_xor((long long)best, mk, 64);
        best = (o < best) ? o : best;
      }
      int j = (int)(best & 0xFFFFFFFFull);
      bi[rsel] = j;
#pragma unroll
      for (int k = 0; k < 16; ++k)
        if (((j >> 6) == k) && ((j & 63) == lane)) kk[k] = 0xFFFFFFFFFFFFFFFFull;
    }
    float mx = 0.f, my = 0.f, mz = 0.f;
#pragma unroll
    for (int k = 1; k <= 16; ++k) {
      float4 q = sp[bi[k]];
      mx = addrn(mx, q.x); my = addrn(my, q.y); mz = addrn(mz, q.z);
    }
    mx = mulrn(mx, 0.0625f); my = mulrn(my, 0.0625f); mz = mulrn(mz, 0.0625f);
    float c00 = 0.f, c01 = 0.f, c02 = 0.f, c11 = 0.f, c12 = 0.f, c22 = 0.f;
#pragma unroll
    for (int k = 1; k <= 16; ++k) {
      float4 q = sp[bi[k]];
      float dx = subrn(q.x, mx), dy = subrn(q.y, my), dz = subrn(q.z, mz);
      c00 = addrn(c00, mulrn(dx, dx)); c01 = addrn(c01, mulrn(dx, dy));
      c02 = addrn(c02, mulrn(dx, dz)); c11 = addrn(c11, mulrn(dy, dy));
      c12 = addrn(c12, mulrn(dy, dz)); c22 = addrn(c22, mulrn(dz, dz));
    }
    c00 /= 15.f; c01 /= 15.f; c02 /= 15.f; c11 /= 15.f; c12 /= 15.f; c22 /= 15.f;

    float n0, n1, n2;
    eigh3_smallest(c00, c01, c02, c11, c12, c22, n0, n1, n2);
    float nn = __fsqrt_rn(addrn(addrn(mulrn(n0, n0), mulrn(n1, n1)), mulrn(n2, n2)));
    float den = addrn(nn, 1e-8f);
    n0 /= den; n1 /= den; n2 /= den;

    if (lane == 0) {
      int myidx = sample_idx[r];
      float* f = feats9 + r * 9;
      f[0] = pr.x; f[1] = pr.y; f[2] = pr.z;
      f[3] = col[3 * myidx]; f[4] = col[3 * myidx + 1]; f[5] = col[3 * myidx + 2];
      f[6] = n0; f[7] = n1; f[8] = n2;
    }
  }
}

// ---------------- K2b: per-thread MLP (order identical to passing version) ----------------
__global__ __launch_bounds__(64) void k2b_mlp(
    const float* __restrict__ W1, const float* __restrict__ b1,
    const float* __restrict__ W2, const float* __restrict__ b2,
    const float* __restrict__ W3, const float* __restrict__ b3,
    const float* __restrict__ feats9,
    float* __restrict__ featd, int* __restrict__ lbl) {
  __shared__ float hbuf[64][129];
  const int tid = threadIdx.x;
  const int r = blockIdx.x * 64 + tid;
  float f9[9];
#pragma unroll
  for (int k = 0; k < 9; ++k) f9[k] = feats9[r * 9 + k];
  for (int jo = 0; jo < 128; ++jo) {
    float acc = 0.f;
#pragma unroll
    for (int k = 0; k < 9; ++k) acc = fmaf(f9[k], W1[k * 128 + jo], acc);
    acc += b1[jo];
    hbuf[tid][jo] = fmaxf(acc, 0.f);
  }
  float pd[13];
#pragma unroll
  for (int c = 0; c < 13; ++c) pd[c] = 0.f;
  for (int io = 0; io < 128; io += 16) {
    float acc[16];
#pragma unroll
    for (int t = 0; t < 16; ++t) acc[t] = 0.f;
    for (int j = 0; j < 128; ++j) {
      float hj = hbuf[tid][j];
#pragma unroll
      for (int t = 0; t < 16; ++t) acc[t] = fmaf(hj, W2[j * 128 + io + t], acc[t]);
    }
#pragma unroll
    for (int t = 0; t < 16; ++t) {
      float h2 = fmaxf(acc[t] + b2[io + t], 0.f);
#pragma unroll
      for (int c = 0; c < 13; ++c) pd[c] = fmaf(h2, W3[(io + t) * 13 + c], pd[c]);
    }
  }
#pragma unroll
  for (int c = 0; c < 13; ++c) pd[c] += b3[c];
  float mmax = pd[0];
#pragma unroll
  for (int c = 1; c < 13; ++c) mmax = fmaxf(mmax, pd[c]);
  float es = 0.f, ev[13];
#pragma unroll
  for (int c = 0; c < 13; ++c) { ev[c] = expf(pd[c] - mmax); es += ev[c]; }
#pragma unroll
  for (int c = 0; c < 13; ++c) featd[r * 13 + c] = ev[c] / es;
  int am = 0; float bv = pd[0];
#pragma unroll
  for (int c = 1; c < 13; ++c) { if (pd[c] > bv) { bv = pd[c]; am = c; } }
  lbl[r] = am;
}

// ---------------- K3: nearest sample + gather outputs ----------------
__global__ __launch_bounds__(256) void k3_assign(
    const float* __restrict__ pos,
    const float4* __restrict__ sp4g,
    const float* __restrict__ featd,
    const int* __restrict__ lbl,
    float* __restrict__ out) {
  __shared__ float4 sp[NUM_SAMPLE];
  for (int i = threadIdx.x; i < NUM_SAMPLE; i += 256) sp[i] = sp4g[i];
  __syncthreads();
  int i = blockIdx.x * 256 + threadIdx.x;
  float x = pos[3 * i], y = pos[3 * i + 1], z = pos[3 * i + 2];
  float an = addrn(addrn(mulrn(x, x), mulrn(y, y)), mulrn(z, z));
  float bestd = 3.402823466e+38f; int bestj = 0;
#pragma unroll 4
  for (int j = 0; j < NUM_SAMPLE; ++j) {
    float4 q = sp[j];
    float dot = fmaf(z, q.z, fmaf(y, q.y, mulrn(x, q.x)));
    float d2 = subrn(addrn(an, q.w), mulrn(2.f, dot));
    if (d2 < bestd) { bestd = d2; bestj = j; }
  }
  const float* fr = featd + bestj * 13;
  float* o = out + (size_t)i * 13;
#pragma unroll
  for (int c = 0; c < 13; ++c) o[c] = fr[c];
  out[(size_t)N_TOTAL * 13 + i] = (float)lbl[bestj];
}

extern "C" void kernel_launch(void* const* d_in, const int* in_sizes, int n_in,
                              void* d_out, int out_size, void* d_ws, size_t ws_size,
                              hipStream_t stream) {
  (void)in_sizes; (void)n_in; (void)out_size; (void)ws_size;
  const float* pos = (const float*)d_in[0];
  const float* col = (const float*)d_in[1];
  const float* W1 = (const float*)d_in[2];
  const float* b1 = (const float*)d_in[3];
  const float* W2 = (const float*)d_in[4];
  const float* b2 = (const float*)d_in[5];
  const float* W3 = (const float*)d_in[6];
  const float* b3 = (const float*)d_in[7];
  float* out = (float*)d_out;

  char* w = (char*)d_ws;
  unsigned long long* cand = (unsigned long long*)(w);           // 32 KiB (2 sets x 2048)
  int* sample_idx = (int*)(w + 65536);                           //  4 KiB
  float4* sp4g = (float4*)(w + 73728);                           // 16 KiB
  float* featd = (float*)(w + 90112);                            // 52 KiB
  int* lbl = (int*)(w + 143360);                                 //  4 KiB
  float* feats9 = (float*)(w + 147456);                          // 36 KiB

  k0_init<<<16, 256, 0, stream>>>(cand, sample_idx);
  k1_fps<<<FPS_BLOCKS, FPS_THREADS, 0, stream>>>(pos, cand, sample_idx);
  k2a_knn<<<64, 256, 0, stream>>>(pos, col, sample_idx, sp4g, feats9);
  k2b_mlp<<<16, 64, 0, stream>>>(W1, b1, W2, b2, W3, b3, feats9, featd, lbl);
  k3_assign<<<N_TOTAL / 256, 256, 0, stream>>>(pos, sp4g, featd, lbl, out);
}

// Round 10
// 1928.698 us; speedup vs baseline: 1.5285x; 1.5285x over previous
//
#include <hip/hip_runtime.h>
#include <math.h>

#define N_TOTAL    262144
#define NUM_SAMPLE 1024
#define FPS_BLOCKS 64
#define FPS_THREADS 256
#define FPS_PPT (N_TOTAL / (FPS_BLOCKS * FPS_THREADS))   // 16
#define M_WAVE 8                                          // published cands per wave
#define POOL (FPS_BLOCKS * 4 * M_WAVE)                    // 2048
#define ENT_PER_T (POOL / FPS_THREADS)                    // 8
#define SEL_CAP 1023

__device__ __forceinline__ float addrn(float a, float b) { return __fadd_rn(a, b); }
__device__ __forceinline__ float subrn(float a, float b) { return __fsub_rn(a, b); }
__device__ __forceinline__ float mulrn(float a, float b) { return __fmul_rn(a, b); }

__device__ __forceinline__ float d2rn(float ax, float ay, float az,
                                      float bx, float by, float bz) {
  float dx = subrn(ax, bx), dy = subrn(ay, by), dz = subrn(az, bz);
  return addrn(addrn(mulrn(dx, dx), mulrn(dy, dy)), mulrn(dz, dz));
}

__device__ __forceinline__ unsigned long long shflxor_u64(unsigned long long v, int mk) {
  return (unsigned long long)__shfl_xor((long long)v, mk, 64);
}

// ---- DPP wave64 max-reduce + SGPR broadcast (no LDS pipe, pure VALU) ----
template <int CTRL>
__device__ __forceinline__ int dpp_i(int x) {
  return __builtin_amdgcn_update_dpp(x, x, CTRL, 0xF, 0xF, false);
}
__device__ __forceinline__ float wave_fmax_bcast(float v) {
  v = fmaxf(v, __int_as_float(dpp_i<0x111>(__float_as_int(v))));   // row_shr:1
  v = fmaxf(v, __int_as_float(dpp_i<0x112>(__float_as_int(v))));   // row_shr:2
  v = fmaxf(v, __int_as_float(dpp_i<0x114>(__float_as_int(v))));   // row_shr:4
  v = fmaxf(v, __int_as_float(dpp_i<0x118>(__float_as_int(v))));   // row_shr:8
  v = fmaxf(v, __int_as_float(dpp_i<0x142>(__float_as_int(v))));   // row_bcast:15
  v = fmaxf(v, __int_as_float(dpp_i<0x143>(__float_as_int(v))));   // row_bcast:31
  return __int_as_float(__builtin_amdgcn_readlane(__float_as_int(v), 63));
}
__device__ __forceinline__ unsigned wave_umax_bcast(unsigned v) {
  unsigned o;
  o = (unsigned)dpp_i<0x111>((int)v); v = (o > v) ? o : v;
  o = (unsigned)dpp_i<0x112>((int)v); v = (o > v) ? o : v;
  o = (unsigned)dpp_i<0x114>((int)v); v = (o > v) ? o : v;
  o = (unsigned)dpp_i<0x118>((int)v); v = (o > v) ? o : v;
  o = (unsigned)dpp_i<0x142>((int)v); v = (o > v) ? o : v;
  o = (unsigned)dpp_i<0x143>((int)v); v = (o > v) ? o : v;
  return (unsigned)__builtin_amdgcn_readlane((int)v, 63);
}

// ---------------- LAPACK emulation (f32) ----------------
__device__ __forceinline__ float slapy2f(float x, float y) {
  float xa = fabsf(x), ya = fabsf(y);
  float w = fmaxf(xa, ya), z = fminf(xa, ya);
  if (z == 0.f) return w;
  float t = z / w;
  return w * __fsqrt_rn(1.f + t * t);
}

__device__ __forceinline__ void slartgf(float f, float g, float& c, float& s, float& r) {
  if (g == 0.f) { c = 1.f; s = 0.f; r = f; }
  else if (f == 0.f) { c = 0.f; s = (g > 0.f) ? 1.f : -1.f; r = fabsf(g); }
  else {
    float d = __fsqrt_rn(f * f + g * g);
    c = fabsf(f) / d;
    r = (f >= 0.f) ? d : -d;
    s = g / r;
  }
}

__device__ void slaev2f(float a, float b, float c0, float& rt1, float& rt2,
                        float& cs1, float& sn1) {
  float sm = a + c0, df = a - c0;
  float adf = fabsf(df), tb = b + b, ab = fabsf(tb);
  float acmx, acmn;
  if (fabsf(a) > fabsf(c0)) { acmx = a; acmn = c0; } else { acmx = c0; acmn = a; }
  float rt;
  if (adf > ab)      { float t = ab / adf; rt = adf * __fsqrt_rn(1.f + t * t); }
  else if (adf < ab) { float t = adf / ab; rt = ab * __fsqrt_rn(1.f + t * t); }
  else               { rt = ab * __fsqrt_rn(2.f); }
  int sgn1;
  if (sm < 0.f)      { rt1 = 0.5f * (sm - rt); sgn1 = -1; rt2 = (acmx / rt1) * acmn - (b / rt1) * b; }
  else if (sm > 0.f) { rt1 = 0.5f * (sm + rt); sgn1 = 1;  rt2 = (acmx / rt1) * acmn - (b / rt1) * b; }
  else               { rt1 = 0.5f * rt; rt2 = -0.5f * rt; sgn1 = 1; }
  float cs; int sgn2;
  if (df >= 0.f) { cs = df + rt; sgn2 = 1; } else { cs = df - rt; sgn2 = -1; }
  float acs = fabsf(cs);
  if (acs > ab) {
    float ct = -tb / cs;
    sn1 = 1.f / __fsqrt_rn(1.f + ct * ct);
    cs1 = ct * sn1;
  } else {
    if (ab == 0.f) { cs1 = 1.f; sn1 = 0.f; }
    else { float tn = -cs / tb; cs1 = 1.f / __fsqrt_rn(1.f + tn * tn); sn1 = tn * cs1; }
  }
  if (sgn1 == sgn2) { float tn = cs1; cs1 = -sn1; sn1 = tn; }
}

#define D_(i) d[(i)-1]
#define E_(i) e[(i)-1]

__device__ void ssteqr3(float d[3], float e[2], float Z[3][3]) {
  const float eps    = 5.9604645e-08f;
  const float eps2   = 3.5527137e-15f;
  const float safmin = 1.17549435e-38f;
  const float ssfmax = 3.0744573e+18f;
  const float ssfmin = 3.0517578e-05f;
  const int n = 3;
  int jtot = 0, nmaxit = 90;
  int l1 = 1;

  while (true) {
    if (l1 > n) break;
    if (l1 > 1) E_(l1 - 1) = 0.f;
    int m = n;
    for (int mm = l1; mm <= n - 1; ++mm) {
      float tst = fabsf(E_(mm));
      if (tst == 0.f) { m = mm; break; }
      if (tst <= (__fsqrt_rn(fabsf(D_(mm))) * __fsqrt_rn(fabsf(D_(mm + 1)))) * eps) {
        E_(mm) = 0.f; m = mm; break;
      }
    }
    int l = l1, lsv = l, lend = m, lendsv = m;
    l1 = m + 1;
    if (lend == l) continue;

    float anorm = fabsf(D_(lend));
    for (int i2 = l; i2 <= lend - 1; ++i2) {
      anorm = fmaxf(anorm, fabsf(D_(i2)));
      anorm = fmaxf(anorm, fabsf(E_(i2)));
    }
    int iscale = 0;
    if (anorm == 0.f) continue;
    if (anorm > ssfmax) {
      iscale = 1; float mul = ssfmax / anorm;
      for (int i2 = l; i2 <= lend; ++i2) D_(i2) *= mul;
      for (int i2 = l; i2 <= lend - 1; ++i2) E_(i2) *= mul;
    } else if (anorm < ssfmin) {
      iscale = 2; float mul = ssfmin / anorm;
      for (int i2 = l; i2 <= lend; ++i2) D_(i2) *= mul;
      for (int i2 = l; i2 <= lend - 1; ++i2) E_(i2) *= mul;
    }

    if (fabsf(D_(lend)) < fabsf(D_(l))) { int t = l; l = lend; lend = t; }

    if (lend > l) {
      while (true) {
        int m2 = lend;
        if (l != lend) {
          for (int mm = l; mm <= lend - 1; ++mm) {
            float tst = fabsf(E_(mm)); tst = tst * tst;
            if (tst <= (eps2 * fabsf(D_(mm))) * fabsf(D_(mm + 1)) + safmin) { m2 = mm; break; }
          }
        }
        if (m2 < lend) E_(m2) = 0.f;
        float p = D_(l);
        if (m2 == l) { D_(l) = p; l = l + 1; if (l <= lend) continue; break; }
        if (m2 == l + 1) {
          float rt1, rt2, cc, ss;
          slaev2f(D_(l), E_(l), D_(l + 1), rt1, rt2, cc, ss);
          for (int i2 = 0; i2 < 3; ++i2) {
            float tmp = Z[i2][l];
            Z[i2][l]     = cc * tmp - ss * Z[i2][l - 1];
            Z[i2][l - 1] = ss * tmp + cc * Z[i2][l - 1];
          }
          D_(l) = rt1; D_(l + 1) = rt2; E_(l) = 0.f;
          l = l + 2; if (l <= lend) continue; break;
        }
        if (jtot == nmaxit) break;
        ++jtot;
        float g = (D_(l + 1) - p) / (2.f * E_(l));
        float r = slapy2f(g, 1.f);
        float sgn_rg = (g >= 0.f) ? r : -r;
        g = D_(m2) - p + E_(l) / (g + sgn_rg);
        float s = 1.f, c = 1.f;
        p = 0.f;
        float csv[2], ssv[2];
        for (int i2 = m2 - 1; i2 >= l; --i2) {
          float f = s * E_(i2);
          float b = c * E_(i2);
          slartgf(g, f, c, s, r);
          if (i2 != m2 - 1) E_(i2 + 1) = r;
          g = D_(i2 + 1) - p;
          r = (D_(i2) - g) * s + 2.f * c * b;
          p = s * r;
          D_(i2 + 1) = g + p;
          g = c * r - b;
          csv[i2 - l] = c; ssv[i2 - l] = -s;
        }
        for (int j = m2 - 1; j >= l; --j) {
          float ct = csv[j - l], st = ssv[j - l];
          for (int i2 = 0; i2 < 3; ++i2) {
            float tmp = Z[i2][j];
            Z[i2][j]     = ct * tmp - st * Z[i2][j - 1];
            Z[i2][j - 1] = st * tmp + ct * Z[i2][j - 1];
          }
        }
        D_(l) = D_(l) - p;
        E_(l) = g;
      }
    } else {
      while (true) {
        int m2 = lend;
        if (l != lend) {
          for (int mm = l; mm >= lend + 1; --mm) {
            float tst = fabsf(E_(mm - 1)); tst = tst * tst;
            if (tst <= (eps2 * fabsf(D_(mm))) * fabsf(D_(mm - 1)) + safmin) { m2 = mm; break; }
          }
        }
        if (m2 > lend) E_(m2 - 1) = 0.f;
        float p = D_(l);
        if (m2 == l) { D_(l) = p; l = l - 1; if (l >= lend) continue; break; }
        if (m2 == l - 1) {
          float rt1, rt2, cc, ss;
          slaev2f(D_(l - 1), E_(l - 1), D_(l), rt1, rt2, cc, ss);
          for (int i2 = 0; i2 < 3; ++i2) {
            float tmp = Z[i2][l - 1];
            Z[i2][l - 1] = cc * tmp - ss * Z[i2][l - 2];
            Z[i2][l - 2] = ss * tmp + cc * Z[i2][l - 2];
          }
          D_(l - 1) = rt1; D_(l) = rt2; E_(l - 1) = 0.f;
          l = l - 2; if (l >= lend) continue; break;
        }
        if (jtot == nmaxit) break;
        ++jtot;
        float g = (D_(l - 1) - p) / (2.f * E_(l - 1));
        float r = slapy2f(g, 1.f);
        float sgn_rg = (g >= 0.f) ? r : -r;
        g = D_(m2) - p + E_(l - 1) / (g + sgn_rg);
        float s = 1.f, c = 1.f;
        p = 0.f;
        float csv[2], ssv[2];
        for (int i2 = m2; i2 <= l - 1; ++i2) {
          float f = s * E_(i2);
          float b = c * E_(i2);
          slartgf(g, f, c, s, r);
          if (i2 != m2) E_(i2 - 1) = r;
          g = D_(i2) - p;
          r = (D_(i2 + 1) - g) * s + 2.f * c * b;
          p = s * r;
          D_(i2) = g + p;
          g = c * r - b;
          csv[i2 - m2] = c; ssv[i2 - m2] = s;
        }
        for (int j = m2; j <= l - 1; ++j) {
          float ct = csv[j - m2], st = ssv[j - m2];
          for (int i2 = 0; i2 < 3; ++i2) {
            float tmp = Z[i2][j];
            Z[i2][j]     = ct * tmp - st * Z[i2][j - 1];
            Z[i2][j - 1] = st * tmp + ct * Z[i2][j - 1];
          }
        }
        D_(l) = D_(l) - p;
        E_(l - 1) = g;
      }
    }
    if (iscale == 1) {
      float mul = anorm / ssfmax;
      for (int i2 = lsv; i2 <= lendsv; ++i2) D_(i2) *= mul;
      for (int i2 = lsv; i2 <= lendsv - 1; ++i2) E_(i2) *= mul;
    } else if (iscale == 2) {
      float mul = anorm / ssfmin;
      for (int i2 = lsv; i2 <= lendsv; ++i2) D_(i2) *= mul;
      for (int i2 = lsv; i2 <= lendsv - 1; ++i2) E_(i2) *= mul;
    }
  }
  for (int ii = 2; ii <= n; ++ii) {
    int i2 = ii - 1, k = i2;
    float p = D_(i2);
    for (int j = ii; j <= n; ++j) if (D_(j) < p) { k = j; p = D_(j); }
    if (k != i2) {
      D_(k) = D_(i2); D_(i2) = p;
      for (int rr = 0; rr < 3; ++rr) {
        float t = Z[rr][i2 - 1]; Z[rr][i2 - 1] = Z[rr][k - 1]; Z[rr][k - 1] = t;
      }
    }
  }
}

__device__ void eigh3_smallest(float a00, float a10, float a20, float a11, float a21, float a22,
                               float& nx, float& ny, float& nz) {
  float d[3], e[2];
  float Z[3][3] = {{1.f,0.f,0.f},{0.f,1.f,0.f},{0.f,0.f,1.f}};
  float tau, v2;
  {
    float alpha = a10, x = a20;
    float xnorm = fabsf(x);
    if (xnorm == 0.f) {
      tau = 0.f; v2 = 0.f;
      d[0] = a00; d[1] = a11; d[2] = a22;
      e[0] = alpha; e[1] = a21;
    } else {
      float beta = -copysignf(slapy2f(alpha, x), alpha);
      tau = (beta - alpha) / beta;
      v2 = x / (alpha - beta);
      float w0 = (tau * a11) + tau * (a21 * v2);
      float w1 = (tau * a21) + (tau * v2) * a22;
      float ac = (-0.5f * tau) * (w0 + w1 * v2);
      w0 = w0 + ac;
      w1 = w1 + ac * v2;
      d[0] = a00;
      d[1] = (a11 - w0) - w0;
      d[2] = (a22 - v2 * w1) - w1 * v2;
      e[0] = beta;
      e[1] = (a21 - v2 * w0) - w1;
    }
  }
  ssteqr3(d, e, Z);
  if (tau != 0.f) {
    for (int c = 0; c < 3; ++c) {
      float w = Z[1][c] + Z[2][c] * v2;
      float temp = (-tau) * w;
      Z[1][c] = Z[1][c] + temp;
      Z[2][c] = Z[2][c] + v2 * temp;
    }
  }
  nx = Z[0][0]; ny = Z[1][0]; nz = Z[2][0];
}

// ---------------- K0: init workspace ----------------
__global__ void k0_init(unsigned long long* cand, int* sample_idx) {
  int t = blockIdx.x * blockDim.x + threadIdx.x;
  if (t < 2 * POOL) cand[t] = 0ull;
  if (t == 0) sample_idx[0] = 0;
}

// ---------------- K1: batched FPS, DPP reduces, owner-relayed xyz ----------------
// Candidates carried as (md f32, idf u32) where idf = 0x3FFFFF - point_index
// (md>=0 so f32 order == bit order; idf unique per point -> exact lex order,
//  larger md wins, ties -> smaller point index). Per batch: per-wave top-8 via
// DPP two-stage argmax -> publish 8 tagged words/wave -> poll own wave's words
// -> pick loop: local 8-scan + DPP wave argmax + owner writes (md,idf,xyz) from
// registers to LDS wave record + 1 barrier + uniform 4-way merge. T-bound as
// before (max over 256 waves of their 8th-best) -> picks bit-exact.
__global__ __launch_bounds__(FPS_THREADS) void k1_fps(
    const float* __restrict__ pos,
    unsigned long long* __restrict__ cand,
    int* __restrict__ sample_idx) {
  __shared__ float sel_x[SEL_CAP], sel_y[SEL_CAP], sel_z[SEL_CAP];
  __shared__ float wb_md[2][4], wb_x[2][4], wb_y[2][4], wb_z[2][4];
  __shared__ unsigned wb_idf[2][4];
  __shared__ float tred_md[4];
  __shared__ unsigned tred_idf[4];
  __shared__ int sh_selcnt;

  const int tidx = threadIdx.x;
  const int lane = tidx & 63, wv = tidx >> 6;
  const int gtid = blockIdx.x * FPS_THREADS + tidx;

  float px[FPS_PPT], py[FPS_PPT], pz[FPS_PPT], md[FPS_PPT];
#pragma unroll
  for (int k = 0; k < FPS_PPT; ++k) {
    int p = gtid + k * (FPS_BLOCKS * FPS_THREADS);
    px[k] = pos[3 * p]; py[k] = pos[3 * p + 1]; pz[k] = pos[3 * p + 2];
    md[k] = 1e10f;
  }
  const unsigned idf0 = 0x3FFFFFu - (unsigned)gtid;
  if (tidx == 0) { sel_x[0] = pos[0]; sel_y[0] = pos[1]; sel_z[0] = pos[2]; }
  __syncthreads();
  int sel_cnt = 1, total = 0, bt = 0;
  while (total < NUM_SAMPLE - 1) {
    ++bt;
    // ---- Phase A: owner md updates vs previous batch's picks ----
    for (int s = 0; s < sel_cnt; ++s) {
      float lx = sel_x[s], ly = sel_y[s], lz = sel_z[s];
#pragma unroll
      for (int k = 0; k < FPS_PPT; ++k)
        md[k] = fminf(md[k], d2rn(px[k], py[k], pz[k], lx, ly, lz));
    }
    // ---- per-wave top-8 via DPP (registers only, barrier-free) ----
    const unsigned tag = (unsigned)bt & 1023u;
    unsigned long long* setbase = cand + (size_t)(bt & 1) * POOL;
    {
      float wmd[FPS_PPT];
#pragma unroll
      for (int k = 0; k < FPS_PPT; ++k) wmd[k] = md[k];
      unsigned long long mypub = 0ull;
      for (int r = 0; r < M_WAVE; ++r) {
        float bm = wmd[0]; unsigned bidf = idf0;
#pragma unroll
        for (int k = 1; k < FPS_PPT; ++k) {
          unsigned idfk = idf0 - ((unsigned)k << 14);
          if (wmd[k] > bm || (wmd[k] == bm && idfk > bidf)) { bm = wmd[k]; bidf = idfk; }
        }
        float wmx = wave_fmax_bcast(bm);
        unsigned tb = (bm == wmx) ? bidf : 0u;
        unsigned widf = wave_umax_bcast(tb);
        if (lane == r)
          mypub = ((unsigned long long)__float_as_uint(wmx) << 32) |
                  ((unsigned long long)widf << 10);
#pragma unroll
        for (int k = 0; k < FPS_PPT; ++k) {
          unsigned idfk = idf0 - ((unsigned)k << 14);
          if (wmd[k] == wmx && idfk == widf) wmd[k] = -1.f;
        }
      }
      if (lane < M_WAVE)
        __hip_atomic_store(setbase + blockIdx.x * (4 * M_WAVE) + wv * M_WAVE + lane,
                           mypub | tag, __ATOMIC_RELAXED, __HIP_MEMORY_SCOPE_AGENT);
    }
    // ---- Phase B: poll own 8 words (thread t holds global wave t's top-8) ----
    const int base_w = tidx * ENT_PER_T;
    float cmd[ENT_PER_T]; unsigned cidf[ENT_PER_T];
    {
      unsigned done = 0;
      while (done != 0xFFu) {
#pragma unroll
        for (int j = 0; j < ENT_PER_T; ++j) {
          if (!((done >> j) & 1u)) {
            unsigned long long v = __hip_atomic_load(setbase + base_w + j,
                                                     __ATOMIC_RELAXED, __HIP_MEMORY_SCOPE_AGENT);
            if ((unsigned)(v & 1023ull) == tag) {
              done |= 1u << j;
              cmd[j] = __uint_as_float((unsigned)(v >> 32));
              cidf[j] = (unsigned)((v >> 10) & 0x3FFFFFull);
            }
          }
        }
        if (done != 0xFFu) __builtin_amdgcn_s_sleep(1);
      }
    }
    // ---- fetch candidate xyz (bit-exact from pos, L2/L3-warm) ----
    float cx[ENT_PER_T], cy[ENT_PER_T], cz[ENT_PER_T];
#pragma unroll
    for (int j = 0; j < ENT_PER_T; ++j) {
      int gidx = 0x3FFFFF - (int)cidf[j];
      cx[j] = pos[3 * gidx]; cy[j] = pos[3 * gidx + 1]; cz[j] = pos[3 * gidx + 2];
    }
    // ---- T = max over 256 waves of their 8th-best (DPP + LDS merge) ----
    {
      float t7 = cmd[ENT_PER_T - 1]; unsigned t7i = cidf[ENT_PER_T - 1];
      float twm = wave_fmax_bcast(t7);
      unsigned ttb = (t7 == twm) ? t7i : 0u;
      unsigned twi = wave_umax_bcast(ttb);
      if (lane == 0) { tred_md[wv] = twm; tred_idf[wv] = twi; }
    }
    __syncthreads();
    float Tmd = tred_md[0]; unsigned Tidf = tred_idf[0];
#pragma unroll
    for (int w = 1; w < 4; ++w) {
      float m2 = tred_md[w]; unsigned i2v = tred_idf[w];
      if (m2 > Tmd || (m2 == Tmd && i2v > Tidf)) { Tmd = m2; Tidf = i2v; }
    }
    // ---- Phase C: pick loop — DPP argmax, owner-relayed xyz, 1 barrier/pick ----
    int picks = 0;
    const int room = (NUM_SAMPLE - 1) - total;
    for (;;) {
      const int q = picks & 1;
      float bm = cmd[0]; unsigned bidf = cidf[0]; int bj = 0;
#pragma unroll
      for (int j = 1; j < ENT_PER_T; ++j)
        if (cmd[j] > bm || (cmd[j] == bm && cidf[j] > bidf)) { bm = cmd[j]; bidf = cidf[j]; bj = j; }
      float wmx = wave_fmax_bcast(bm);
      unsigned tb = (bm == wmx) ? bidf : 0u;
      unsigned widf = wave_umax_bcast(tb);
      if (bm == wmx && bidf == widf) {          // unique owner lane in this wave
        wb_md[q][wv] = wmx; wb_idf[q][wv] = widf;
        wb_x[q][wv] = cx[bj]; wb_y[q][wv] = cy[bj]; wb_z[q][wv] = cz[bj];
      }
      __syncthreads();
      float gm = wb_md[q][0]; unsigned gi = wb_idf[q][0]; int gw = 0;
#pragma unroll
      for (int w = 1; w < 4; ++w) {
        float m2 = wb_md[q][w]; unsigned i2v = wb_idf[q][w];
        if (m2 > gm || (m2 == gm && i2v > gi)) { gm = m2; gi = i2v; gw = w; }
      }
      if ((gm < Tmd || (gm == Tmd && gi < Tidf)) || picks >= room) break;
      float Xp = wb_x[q][gw], Yp = wb_y[q][gw], Zp = wb_z[q][gw];
      if (tidx == 0) {
        sel_x[picks] = Xp; sel_y[picks] = Yp; sel_z[picks] = Zp;
        if (blockIdx.x == 0) sample_idx[1 + total + picks] = 0x3FFFFF - (int)gi;
      }
#pragma unroll
      for (int j = 0; j < ENT_PER_T; ++j) {
        if (cmd[j] == gm && cidf[j] == gi) cmd[j] = -1.f;   // remove winner
        float d2 = d2rn(cx[j], cy[j], cz[j], Xp, Yp, Zp);
        if (d2 < cmd[j]) cmd[j] = d2;                       // exact min update
      }
      ++picks;
    }
    if (tidx == 0) sh_selcnt = picks;
    __syncthreads();
    sel_cnt = sh_selcnt;
    total += sel_cnt;
  }
}

// ---------------- K2a: wave-per-sample KNN + covariance + eigh -> feats9 ----------------
__global__ __launch_bounds__(256) void k2a_knn(
    const float* __restrict__ pos, const float* __restrict__ col,
    const int* __restrict__ sample_idx,
    float4* __restrict__ sp4g, float* __restrict__ feats9) {
  __shared__ float4 sp[NUM_SAMPLE];
  const int tid = threadIdx.x, lane = tid & 63, wv = tid >> 6;
  for (int i = tid; i < NUM_SAMPLE; i += 256) {
    int idx = sample_idx[i];
    float x = pos[3 * idx], y = pos[3 * idx + 1], z = pos[3 * idx + 2];
    float nrm = addrn(addrn(mulrn(x, x), mulrn(y, y)), mulrn(z, z));
    float4 v = make_float4(x, y, z, nrm);
    sp[i] = v;
    if (blockIdx.x == 0) sp4g[i] = v;
  }
  __syncthreads();
  for (int it = 0; it < 4; ++it) {
    const int r = blockIdx.x * 16 + wv * 4 + it;
    float4 pr = sp[r];
    unsigned long long kk[16];
#pragma unroll
    for (int k = 0; k < 16; ++k) {
      int j = lane + 64 * k;
      float4 q = sp[j];
      float dot = fmaf(pr.z, q.z, fmaf(pr.y, q.y, mulrn(pr.x, q.x)));
      float d2 = subrn(addrn(pr.w, q.w), mulrn(2.f, dot));
      unsigned b = __float_as_uint(d2);
      unsigned sbits = (b & 0x80000000u) ? ~b : (b | 0x80000000u);
      kk[k] = ((unsigned long long)sbits << 32) | (unsigned)j;
    }
    int bi[17];
#pragma unroll
    for (int rsel = 0; rsel < 17; ++rsel) {
      unsigned long long best = 0xFFFFFFFFFFFFFFFFull;
#pragma unroll
      for (int k = 0; k < 16; ++k) best = (kk[k] < best) ? kk[k] : best;
#pragma unroll
      for (int mk = 1; mk < 64; mk <<= 1) {
        unsigned long long o = (unsigned long long)__shfl_xor((long long)best, mk, 64);
        best = (o < best) ? o : best;
      }
      int j = (int)(best & 0xFFFFFFFFull);
      bi[rsel] = j;
#pragma unroll
      for (int k = 0; k < 16; ++k)
        if (((j >> 6) == k) && ((j & 63) == lane)) kk[k] = 0xFFFFFFFFFFFFFFFFull;
    }
    float mx = 0.f, my = 0.f, mz = 0.f;
#pragma unroll
    for (int k = 1; k <= 16; ++k) {
      float4 q = sp[bi[k]];
      mx = addrn(mx, q.x); my = addrn(my, q.y); mz = addrn(mz, q.z);
    }
    mx = mulrn(mx, 0.0625f); my = mulrn(my, 0.0625f); mz = mulrn(mz, 0.0625f);
    float c00 = 0.f, c01 = 0.f, c02 = 0.f, c11 = 0.f, c12 = 0.f, c22 = 0.f;
#pragma unroll
    for (int k = 1; k <= 16; ++k) {
      float4 q = sp[bi[k]];
      float dx = subrn(q.x, mx), dy = subrn(q.y, my), dz = subrn(q.z, mz);
      c00 = addrn(c00, mulrn(dx, dx)); c01 = addrn(c01, mulrn(dx, dy));
      c02 = addrn(c02, mulrn(dx, dz)); c11 = addrn(c11, mulrn(dy, dy));
      c12 = addrn(c12, mulrn(dy, dz)); c22 = addrn(c22, mulrn(dz, dz));
    }
    c00 /= 15.f; c01 /= 15.f; c02 /= 15.f; c11 /= 15.f; c12 /= 15.f; c22 /= 15.f;

    float n0, n1, n2;
    eigh3_smallest(c00, c01, c02, c11, c12, c22, n0, n1, n2);
    float nn = __fsqrt_rn(addrn(addrn(mulrn(n0, n0), mulrn(n1, n1)), mulrn(n2, n2)));
    float den = addrn(nn, 1e-8f);
    n0 /= den; n1 /= den; n2 /= den;

    if (lane == 0) {
      int myidx = sample_idx[r];
      float* f = feats9 + r * 9;
      f[0] = pr.x; f[1] = pr.y; f[2] = pr.z;
      f[3] = col[3 * myidx]; f[4] = col[3 * myidx + 1]; f[5] = col[3 * myidx + 2];
      f[6] = n0; f[7] = n1; f[8] = n2;
    }
  }
}

// ---------------- K2b: per-thread MLP (order identical to passing version) ----------------
__global__ __launch_bounds__(64) void k2b_mlp(
    const float* __restrict__ W1, const float* __restrict__ b1,
    const float* __restrict__ W2, const float* __restrict__ b2,
    const float* __restrict__ W3, const float* __restrict__ b3,
    const float* __restrict__ feats9,
    float* __restrict__ featd, int* __restrict__ lbl) {
  __shared__ float hbuf[64][129];
  const int tid = threadIdx.x;
  const int r = blockIdx.x * 64 + tid;
  float f9[9];
#pragma unroll
  for (int k = 0; k < 9; ++k) f9[k] = feats9[r * 9 + k];
  for (int jo = 0; jo < 128; ++jo) {
    float acc = 0.f;
#pragma unroll
    for (int k = 0; k < 9; ++k) acc = fmaf(f9[k], W1[k * 128 + jo], acc);
    acc += b1[jo];
    hbuf[tid][jo] = fmaxf(acc, 0.f);
  }
  float pd[13];
#pragma unroll
  for (int c = 0; c < 13; ++c) pd[c] = 0.f;
  for (int io = 0; io < 128; io += 16) {
    float acc[16];
#pragma unroll
    for (int t = 0; t < 16; ++t) acc[t] = 0.f;
    for (int j = 0; j < 128; ++j) {
      float hj = hbuf[tid][j];
#pragma unroll
      for (int t = 0; t < 16; ++t) acc[t] = fmaf(hj, W2[j * 128 + io + t], acc[t]);
    }
#pragma unroll
    for (int t = 0; t < 16; ++t) {
      float h2 = fmaxf(acc[t] + b2[io + t], 0.f);
#pragma unroll
      for (int c = 0; c < 13; ++c) pd[c] = fmaf(h2, W3[(io + t) * 13 + c], pd[c]);
    }
  }
#pragma unroll
  for (int c = 0; c < 13; ++c) pd[c] += b3[c];
  float mmax = pd[0];
#pragma unroll
  for (int c = 1; c < 13; ++c) mmax = fmaxf(mmax, pd[c]);
  float es = 0.f, ev[13];
#pragma unroll
  for (int c = 0; c < 13; ++c) { ev[c] = expf(pd[c] - mmax); es += ev[c]; }
#pragma unroll
  for (int c = 0; c < 13; ++c) featd[r * 13 + c] = ev[c] / es;
  int am = 0; float bv = pd[0];
#pragma unroll
  for (int c = 1; c < 13; ++c) { if (pd[c] > bv) { bv = pd[c]; am = c; } }
  lbl[r] = am;
}

// ---------------- K3: nearest sample + gather outputs ----------------
__global__ __launch_bounds__(256) void k3_assign(
    const float* __restrict__ pos,
    const float4* __restrict__ sp4g,
    const float* __restrict__ featd,
    const int* __restrict__ lbl,
    float* __restrict__ out) {
  __shared__ float4 sp[NUM_SAMPLE];
  for (int i = threadIdx.x; i < NUM_SAMPLE; i += 256) sp[i] = sp4g[i];
  __syncthreads();
  int i = blockIdx.x * 256 + threadIdx.x;
  float x = pos[3 * i], y = pos[3 * i + 1], z = pos[3 * i + 2];
  float an = addrn(addrn(mulrn(x, x), mulrn(y, y)), mulrn(z, z));
  float bestd = 3.402823466e+38f; int bestj = 0;
#pragma unroll 4
  for (int j = 0; j < NUM_SAMPLE; ++j) {
    float4 q = sp[j];
    float dot = fmaf(z, q.z, fmaf(y, q.y, mulrn(x, q.x)));
    float d2 = subrn(addrn(an, q.w), mulrn(2.f, dot));
    if (d2 < bestd) { bestd = d2; bestj = j; }
  }
  const float* fr = featd + bestj * 13;
  float* o = out + (size_t)i * 13;
#pragma unroll
  for (int c = 0; c < 13; ++c) o[c] = fr[c];
  out[(size_t)N_TOTAL * 13 + i] = (float)lbl[bestj];
}

extern "C" void kernel_launch(void* const* d_in, const int* in_sizes, int n_in,
                              void* d_out, int out_size, void* d_ws, size_t ws_size,
                              hipStream_t stream) {
  (void)in_sizes; (void)n_in; (void)out_size; (void)ws_size;
  const float* pos = (const float*)d_in[0];
  const float* col = (const float*)d_in[1];
  const float* W1 = (const float*)d_in[2];
  const float* b1 = (const float*)d_in[3];
  const float* W2 = (const float*)d_in[4];
  const float* b2 = (const float*)d_in[5];
  const float* W3 = (const float*)d_in[6];
  const float* b3 = (const float*)d_in[7];
  float* out = (float*)d_out;

  char* w = (char*)d_ws;
  unsigned long long* cand = (unsigned long long*)(w);           // 32 KiB (2 sets x 2048)
  int* sample_idx = (int*)(w + 65536);                           //  4 KiB
  float4* sp4g = (float4*)(w + 73728);                           // 16 KiB
  float* featd = (float*)(w + 90112);                            // 52 KiB
  int* lbl = (int*)(w + 143360);                                 //  4 KiB
  float* feats9 = (float*)(w + 147456);                          // 36 KiB

  k0_init<<<16, 256, 0, stream>>>(cand, sample_idx);
  k1_fps<<<FPS_BLOCKS, FPS_THREADS, 0, stream>>>(pos, cand, sample_idx);
  k2a_knn<<<64, 256, 0, stream>>>(pos, col, sample_idx, sp4g, feats9);
  k2b_mlp<<<16, 64, 0, stream>>>(W1, b1, W2, b2, W3, b3, feats9, featd, lbl);
  k3_assign<<<N_TOTAL / 256, 256, 0, stream>>>(pos, sp4g, featd, lbl, out);
}